// Round 4
// baseline (1245.478 us; speedup 1.0000x reference)
//
#include <hip/hip_runtime.h>
#include <hip/hip_cooperative_groups.h>

namespace cg = cooperative_groups;

#define BB 4
#define CC 84
#define CM 80
#define HH 512
#define WW 512
#define HWSZ (HH * WW)
#define PG (HWSZ / 4)          // 65536 float4 pixel-groups per image

typedef float v4f __attribute__((ext_vector_type(4)));

static __device__ __forceinline__ v4f vmax4(v4f a, v4f b) {
    v4f r;
    r.x = fmaxf(a.x, b.x);
    r.y = fmaxf(a.y, b.y);
    r.z = fmaxf(a.z, b.z);
    r.w = fmaxf(a.w, b.w);
    return r;
}

// ======================= fused cooperative kernel ===========================
// P1: 2 partial channel-max planes (40 ch each)   -> ws[0..8MB)
// P2: combine-on-the-fly + 3x3 NMS mask           -> ws[8MB..12MB)
// P3: out = points * mask (42 ch per work item, NT streams)
__global__ __launch_bounds__(256, 8) void fused_coop(const float* __restrict__ pts,
                                                     float* __restrict__ wsp,
                                                     float* __restrict__ out) {
    float* partial = wsp;                              // 2*BB*HWSZ floats
    float* mask    = wsp + (size_t)2 * BB * HWSZ;      // BB*HWSZ floats
    const int nth  = gridDim.x * 256;
    const int tid0 = blockIdx.x * 256 + threadIdx.x;

    // ---------------- P1: partial max, chunks of 40 channels ---------------
    for (int t = tid0; t < BB * 2 * PG; t += nth) {
        int pg    = t & (PG - 1);
        int r     = t >> 16;            // 0..7
        int b     = r & 3;
        int chunk = r >> 2;             // 0 or 1
        const v4f* base = (const v4f*)pts + ((size_t)b * CC + chunk * 40) * PG + pg;
        v4f m = base[0];                // normal loads: leave tail in L3 for P3
#pragma unroll 8
        for (int c = 1; c < 40; ++c)
            m = vmax4(m, base[(size_t)c * PG]);
        ((v4f*)partial)[((size_t)chunk * BB + b) * PG + pg] = m;
    }
    cg::this_grid().sync();

    // ---------------- P2: 3x3 NMS mask (combine partials on the fly) -------
    // Reference: raster idx < center uses strict >, idx > center uses >=.
    for (int t = tid0; t < BB * PG; t += nth) {
        int pg  = t & (PG - 1);
        int b   = t >> 16;
        int off = pg << 2;
        int h   = off >> 9;
        int w0  = off & (WW - 1);

        const float* p0 = partial + (size_t)b * HWSZ;
        const float* p1 = partial + (size_t)(BB + b) * HWSZ;

        float rows[3][6];
#pragma unroll
        for (int rr = 0; rr < 3; ++rr) {
            int hh = h + rr - 1;
            bool hv = (hh >= 0) & (hh < HH);
#pragma unroll
            for (int ci = 0; ci < 6; ++ci) {
                int ww = w0 + ci - 1;
                bool wv = (ww >= 0) & (ww < WW);
                float v = 0.0f;
                if (hv & wv) {
                    int pidx = hh * WW + ww;
                    v = fmaxf(p0[pidx], p1[pidx]);
                }
                rows[rr][ci] = v;
            }
        }

        v4f fm;
#pragma unroll
        for (int j = 0; j < 4; ++j) {
            float v = rows[1][j + 1];
            bool m = (v >  rows[0][j]) & (v >  rows[0][j + 1]) & (v >  rows[0][j + 2])
                   & (v >  rows[1][j]) & (v >= rows[1][j + 2])
                   & (v >= rows[2][j]) & (v >= rows[2][j + 1]) & (v >= rows[2][j + 2]);
            float f = m ? 1.0f : 0.0f;
            if (j == 0) fm.x = f;
            else if (j == 1) fm.y = f;
            else if (j == 2) fm.z = f;
            else fm.w = f;
        }
        ((v4f*)mask)[(size_t)b * PG + pg] = fm;
    }
    cg::this_grid().sync();

    // ---------------- P3: out = points * mask, 42 channels per item --------
    for (int t = tid0; t < BB * 2 * PG; t += nth) {
        int pg   = t & (PG - 1);
        int r    = t >> 16;             // 0..7
        int b    = r >> 1;
        int half = r & 1;
        v4f m = ((const v4f*)mask)[(size_t)b * PG + pg];
        unsigned nz = (__float_as_uint(m.x) | __float_as_uint(m.y) |
                       __float_as_uint(m.z) | __float_as_uint(m.w));
        size_t base = ((size_t)b * CC + half * 42) * PG + pg;
        if (nz) {
#pragma unroll 7
            for (int j = 0; j < 42; ++j) {
                v4f v = __builtin_nontemporal_load((const v4f*)pts + base + (size_t)j * PG);
                v4f o = v * m;
                __builtin_nontemporal_store(o, (v4f*)out + base + (size_t)j * PG);
            }
        } else {
            v4f z;
            z.x = 0.f; z.y = 0.f; z.z = 0.f; z.w = 0.f;
#pragma unroll 7
            for (int j = 0; j < 42; ++j)
                __builtin_nontemporal_store(z, (v4f*)out + base + (size_t)j * PG);
        }
    }
}

// ======================= fallback: R3 3-kernel path =========================
#define NCH 4
#define CPC (CM / NCH)

__global__ __launch_bounds__(256) void partial_max_kernel(const float* __restrict__ pts,
                                                          float* __restrict__ partial) {
    int tid = blockIdx.x * blockDim.x + threadIdx.x;
    int pg  = tid & (PG - 1);
    int r   = tid >> 16;
    int chunk = r % NCH;
    int b     = r / NCH;
    const v4f* base = (const v4f*)pts + ((size_t)b * CC + chunk * CPC) * PG + pg;
    v4f m = base[0];
#pragma unroll 5
    for (int c = 1; c < CPC; ++c)
        m = vmax4(m, base[(size_t)c * PG]);
    ((v4f*)partial)[((size_t)chunk * BB + b) * PG + pg] = m;
}

__global__ __launch_bounds__(256) void fused_mask_kernel(const float* __restrict__ partial,
                                                         float* __restrict__ mask) {
    int tid = blockIdx.x * blockDim.x + threadIdx.x;
    int pg  = tid & (PG - 1);
    int b   = tid >> 16;
    int off = pg << 2;
    int h   = off >> 9;
    int w0  = off & (WW - 1);

    float rows[3][6];
#pragma unroll
    for (int r = 0; r < 3; ++r) {
        int hh = h + r - 1;
        bool hv = (hh >= 0) & (hh < HH);
#pragma unroll
        for (int ci = 0; ci < 6; ++ci) {
            int ww = w0 + ci - 1;
            bool wv = (ww >= 0) & (ww < WW);
            float v = 0.0f;
            if (hv & wv) {
                int pidx = hh * WW + ww;
                v = partial[(size_t)b * HWSZ + pidx];
#pragma unroll
                for (int ch = 1; ch < NCH; ++ch)
                    v = fmaxf(v, partial[(size_t)(ch * BB + b) * HWSZ + pidx]);
            }
            rows[r][ci] = v;
        }
    }

    v4f fm;
#pragma unroll
    for (int j = 0; j < 4; ++j) {
        float v = rows[1][j + 1];
        bool m = (v >  rows[0][j]) & (v >  rows[0][j + 1]) & (v >  rows[0][j + 2])
               & (v >  rows[1][j]) & (v >= rows[1][j + 2])
               & (v >= rows[2][j]) & (v >= rows[2][j + 1]) & (v >= rows[2][j + 2]);
        float f = m ? 1.0f : 0.0f;
        if (j == 0) fm.x = f;
        else if (j == 1) fm.y = f;
        else if (j == 2) fm.z = f;
        else fm.w = f;
    }
    ((v4f*)mask)[(size_t)b * PG + pg] = fm;
}

__global__ __launch_bounds__(256) void mul_kernel(const float* __restrict__ pts,
                                                  const float* __restrict__ mask,
                                                  float* __restrict__ out) {
    int gid = blockIdx.x;
    int c   = gid % CC;
    int pc  = gid / CC;
    int b   = pc >> 8;
    int pg  = ((pc & 255) << 8) + threadIdx.x;

    v4f m = ((const v4f*)mask)[(size_t)b * PG + pg];
    size_t idx = ((size_t)b * CC + c) * PG + pg;
    unsigned nz = (__float_as_uint(m.x) | __float_as_uint(m.y) |
                   __float_as_uint(m.z) | __float_as_uint(m.w));
    v4f o;
    if (nz) {
        v4f v = __builtin_nontemporal_load((const v4f*)pts + idx);
        o.x = v.x * m.x; o.y = v.y * m.y; o.z = v.z * m.z; o.w = v.w * m.w;
    } else {
        o.x = 0.f; o.y = 0.f; o.z = 0.f; o.w = 0.f;
    }
    __builtin_nontemporal_store(o, (v4f*)out + idx);
}

extern "C" void kernel_launch(void* const* d_in, const int* in_sizes, int n_in,
                              void* d_out, int out_size, void* d_ws, size_t ws_size,
                              hipStream_t stream) {
    const float* pts = (const float*)d_in[0];
    float* out = (float*)d_out;
    float* ws  = (float*)d_ws;

    const size_t MB4 = (size_t)BB * HWSZ * sizeof(float);   // 4 MiB plane

    // ---- preferred: single cooperative kernel (needs 12 MiB ws) ----
    if (ws_size >= 3 * MB4) {
        void* args[] = {(void*)&pts, (void*)&ws, (void*)&out};
        hipError_t e = hipLaunchCooperativeKernel((const void*)fused_coop,
                                                  dim3(2048), dim3(256),
                                                  args, 0, stream);
        if (e != hipSuccess) {
            (void)hipGetLastError();   // clear
            e = hipLaunchCooperativeKernel((const void*)fused_coop,
                                           dim3(1024), dim3(256),
                                           args, 0, stream);
        }
        if (e == hipSuccess) return;
        (void)hipGetLastError();       // clear and fall through
    }

    // ---- fallback: R3 three-kernel path (needs 20 MiB ws) ----
    dim3 blk(256);
    dim3 grd_pg(BB * PG / 256);
    float* partial = ws;
    float* maskp   = ws + (size_t)NCH * BB * HWSZ;
    partial_max_kernel<<<dim3(BB * NCH * PG / 256), blk, 0, stream>>>(pts, partial);
    fused_mask_kernel<<<grd_pg, blk, 0, stream>>>(partial, maskp);
    mul_kernel<<<dim3(BB * CC * (PG / 256)), blk, 0, stream>>>(pts, maskp, out);
}